// Round 10
// baseline (211.876 us; speedup 1.0000x reference)
//
#include <hip/hip_runtime.h>
#include <cstdint>
#include <cstddef>

#define BS      64
#define NPRED   25200
#define KTOP    512
#define MAXDET  300
#define NBINS   4096
#define CAP     1024
#define NTHR    1024
#define CONF_T  0.25f
#define IOU_T   0.45f
#define MAXWH   7680.0f
#define MSTRIDE 18
#define NITER   25

__device__ __forceinline__ unsigned long long shflx64(unsigned long long v, int m) {
  unsigned lo = __shfl_xor((unsigned)(v & 0xffffffffull), m, 64);
  unsigned hi = __shfl_xor((unsigned)(v >> 32), m, 64);
  return (((unsigned long long)hi) << 32) | lo;
}

__device__ __forceinline__ float scoreOf(const float4& q) {
  return fmaxf(q.x * q.y, fmaxf(q.x * q.z, q.x * q.w));
}

// ================= PROBE 0: phase-A loads ONLY (no LDS) =====================
__global__ __launch_bounds__(NTHR) void probe_load_k(const float* __restrict__ pred,
                                                     float* __restrict__ wsl) {
  const int tid = threadIdx.x, img = blockIdx.x;
  const float* __restrict__ base = pred + (size_t)img * (NPRED * 8);
  float acc = 0.0f;
#pragma unroll
  for (int it = 0; it < NITER; ++it) {
    const int e = tid + (it << 10);
    if (e < NPRED) {
      const float4 q = *reinterpret_cast<const float4*>(base + (size_t)e * 8 + 4);
      acc += scoreOf(q);
    }
  }
  wsl[(size_t)img * NTHR + tid] = acc;
}

// ================= PROBE 1: phases A+suffix+B (score/hist/collect) ==========
__global__ __launch_bounds__(NTHR) void probe_scan_k(const float* __restrict__ pred,
                                                     unsigned long long* __restrict__ wsk) {
  __shared__ unsigned int hist[NBINS];
  __shared__ unsigned long long keysL[CAP];
  __shared__ unsigned int wtot[16];
  __shared__ int cutoff_s, cnt_s;
  const int tid = threadIdx.x, lane = tid & 63, wid = tid >> 6, img = blockIdx.x;
  const float* __restrict__ base = pred + (size_t)img * (NPRED * 8);
  if (tid == 0) cnt_s = 0;
  for (int b = tid; b < NBINS; b += NTHR) hist[b] = 0u;
  __syncthreads();
  float sc[NITER];
#pragma unroll
  for (int it = 0; it < NITER; ++it) {
    const int e = tid + (it << 10);
    float m = -1.0f;
    if (e < NPRED) {
      const float4 q = *reinterpret_cast<const float4*>(base + (size_t)e * 8 + 4);
      m = scoreOf(q);
      int b = min(max((int)(m * (float)NBINS), 0), NBINS - 1);
      atomicAdd(&hist[b], 1u);
    }
    sc[it] = m;
  }
  __syncthreads();
  const uint4 h = *reinterpret_cast<const uint4*>(hist + (tid << 2));
  unsigned g = h.x + h.y + h.z + h.w;
  unsigned s = g;
#pragma unroll
  for (int d = 1; d < 64; d <<= 1) {
    unsigned o = __shfl_down(s, d, 64);
    if (lane + d < 64) s += o;
  }
  if (lane == 0) wtot[wid] = s;
  __syncthreads();
  if (tid < 16) {
    unsigned t = wtot[tid];
#pragma unroll
    for (int d = 1; d < 16; d <<= 1) {
      unsigned o = __shfl_down(t, d, 64);
      if (tid + d < 16) t += o;
    }
    wtot[tid] = t;
  }
  __syncthreads();
  unsigned S = s + ((wid < 15) ? wtot[wid + 1] : 0u);
  if (S >= KTOP && (S - g) < KTOP) {
    unsigned acc = S - g;
    int cut;
    acc += h.w;
    if (acc >= KTOP) cut = 4 * tid + 3;
    else { acc += h.z;
      if (acc >= KTOP) cut = 4 * tid + 2;
      else { acc += h.y;
        if (acc >= KTOP) cut = 4 * tid + 1; else cut = 4 * tid; } }
    cutoff_s = cut;
  }
  __syncthreads();
  const int cutoff = cutoff_s;
#pragma unroll
  for (int it = 0; it < NITER; ++it) {
    const int e = tid + (it << 10);
    if (e < NPRED) {
      float m = sc[it];
      int b = min(max((int)(m * (float)NBINS), 0), NBINS - 1);
      if (b >= cutoff) {
        int p = atomicAdd(&cnt_s, 1);
        if (p < CAP) keysL[p] = (((unsigned long long)__float_as_uint(m)) << 32)
                              | (unsigned)(0x7FFFFFFF - e);
      }
    }
  }
  __syncthreads();
  const int cnt = min(cnt_s, CAP);
  wsk[(size_t)img * CAP + tid] = (tid < cnt) ? keysL[tid] : (unsigned long long)cnt;
}

// ================= PROBE 2: phase C alone (hybrid bitonic sort) =============
__global__ __launch_bounds__(NTHR) void probe_sort_k(unsigned long long* __restrict__ wsj) {
  __shared__ unsigned long long keysL[CAP];
  const int tid = threadIdx.x;
  const int img = blockIdx.x;
  unsigned long long* my = wsj + (size_t)img * CAP;
  // deterministic varied keys from poisoned ws (0xAA..) ^ hash(tid)
  unsigned long long key = my[tid] ^ ((unsigned long long)(tid * 2654435761u) << 16) ^ (unsigned)tid;
  for (int k = 2; k <= CAP; k <<= 1) {
    for (int j = k >> 1; j > 0; j >>= 1) {
      unsigned long long p;
      if (j >= 64) {
        __syncthreads();
        keysL[tid] = key;
        __syncthreads();
        p = keysL[tid ^ j];
      } else {
        p = shflx64(key, j);
      }
      bool lower = ((tid & j) == 0);
      bool descR = ((tid & k) == 0);
      bool takeMax = (lower == descR);
      bool pGreater = (p > key);
      key = (takeMax == pGreater) ? p : key;
    }
  }
  my[tid] = key;
}

// ================= PROBE 3: phases D+E+F (boxes/mask/greedy) ================
__global__ __launch_bounds__(NTHR) void probe_mask_k(const float* __restrict__ pred,
                                                     unsigned int* __restrict__ wso) {
  __shared__ __align__(16) unsigned int maskA[KTOP * MSTRIDE];
  __shared__ float ox0[KTOP], oy0[KTOP], ox1[KTOP], oy1[KTOP], areaL[KTOP];
  __shared__ unsigned int supW[16];
  const int tid = threadIdx.x, lane = tid & 63, wid = tid >> 6, img = blockIdx.x;
  const float* __restrict__ base = pred + (size_t)img * (NPRED * 8);
  if (tid < KTOP) {                       // boxes from anchors tid directly
    const float4 a = *reinterpret_cast<const float4*>(base + (size_t)tid * 8);
    const float4 q = *reinterpret_cast<const float4*>(base + (size_t)tid * 8 + 4);
    float p0 = q.x * q.y, p1 = q.x * q.z, p2 = q.x * q.w;
    float m = fmaxf(p0, fmaxf(p1, p2));
    int c = (p0 == m) ? 0 : ((p1 == m) ? 1 : 2);
    float x0 = a.x - a.z * 0.5f, y0 = a.y - a.w * 0.5f;
    float x1 = a.x + a.z * 0.5f, y1 = a.y + a.w * 0.5f;
    float co = (float)c * MAXWH;
    float o0 = x0 + co, o1 = y0 + co, o2 = x1 + co, o3 = y1 + co;
    ox0[tid] = o0; oy0[tid] = o1; ox1[tid] = o2; oy1[tid] = o3;
    areaL[tid] = (o2 - o0) * (o3 - o1);
  }
  __syncthreads();
  for (int w = tid; w < KTOP * MSTRIDE; w += NTHR) maskA[w] = 0u;
  __syncthreads();
  for (int jb = 0; jb < 8; ++jb) {
    const int j = (jb << 6) + lane;
    const float jx0 = ox0[j], jy0 = oy0[j], jx1 = ox1[j], jy1 = oy1[j];
    const float ja = areaL[j];
    const int ilim = (jb + 1) << 6;
    for (int i = wid; i < ilim; i += 16) {
      float xx0 = fmaxf(ox0[i], jx0), yy0 = fmaxf(oy0[i], jy0);
      float xx1 = fminf(ox1[i], jx1), yy1 = fminf(oy1[i], jy1);
      float iw = fmaxf(xx1 - xx0, 0.0f), ih = fmaxf(yy1 - yy0, 0.0f);
      float inter = iw * ih;
      float denom = areaL[i] + ja - inter + 1e-7f;
      bool sup = (inter > IOU_T * denom) && (j > i);
      unsigned long long bal = __ballot(sup);
      if (lane == 0)
        *reinterpret_cast<unsigned long long*>(maskA + i * MSTRIDE + (jb << 1)) = bal;
    }
  }
  __syncthreads();
  if (tid < 16) {
    unsigned sst = 0u;
    for (int c = 0; c < KTOP / 16; ++c) {
      const int rb = c * 16, wi = rb >> 5, b0 = rb & 31;
      unsigned myrow[16], diag[16];
#pragma unroll
      for (int r = 0; r < 16; ++r) {
        myrow[r] = maskA[(rb + r) * MSTRIDE + tid];
        diag[r]  = maskA[(rb + r) * MSTRIDE + wi];
      }
      unsigned wcur = __shfl(sst, wi, 64);
#pragma unroll
      for (int r = 0; r < 16; ++r) {
        if (!((wcur >> (b0 + r)) & 1u)) { sst |= myrow[r]; wcur |= diag[r]; }
      }
    }
    supW[tid] = sst;
  }
  __syncthreads();
  if (tid < 16) wso[(size_t)img * 16 + tid] = supW[tid];
}

// ================= MAIN: byte-identical to R7 (proven, 78 us) ===============
__global__ __launch_bounds__(NTHR) void yolo_k(const float* __restrict__ pred,
                                               float* __restrict__ out) {
  __shared__ unsigned long long keysL[CAP];
  __shared__ __align__(16) unsigned int maskA[KTOP * MSTRIDE];
  __shared__ float ox0[KTOP], oy0[KTOP], ox1[KTOP], oy1[KTOP], areaL[KTOP];
  __shared__ float bx0[KTOP], bx1[KTOP], bx2[KTOP], bx3[KTOP];
  __shared__ float svL[KTOP]; __shared__ int siL[KTOP]; __shared__ int cidL[KTOP];
  __shared__ unsigned int supW[16];
  __shared__ unsigned int wtot[16];
  __shared__ int woff[8];
  __shared__ int cutoff_s, cnt_s, nvalid_s;

  unsigned int* hist = maskA;

  const int tid = threadIdx.x;
  const int lane = tid & 63;
  const int wid = tid >> 6;
  const int img = blockIdx.x;
  const float* __restrict__ base = pred + (size_t)img * (NPRED * 8);

  if (tid == 0) cnt_s = 0;

  for (int b = tid; b < NBINS; b += NTHR) hist[b] = 0u;
  __syncthreads();
  float sc[NITER];
#pragma unroll
  for (int it = 0; it < NITER; ++it) {
    const int e = tid + (it << 10);
    float m = -1.0f;
    if (e < NPRED) {
      const float4 q = *reinterpret_cast<const float4*>(base + (size_t)e * 8 + 4);
      m = scoreOf(q);
      int b = (int)(m * (float)NBINS);
      b = min(max(b, 0), NBINS - 1);
      atomicAdd(&hist[b], 1u);
    }
    sc[it] = m;
  }
  __syncthreads();
  const uint4 h = *reinterpret_cast<const uint4*>(hist + (tid << 2));
  const unsigned h0 = h.x, h1 = h.y, h2 = h.z, h3 = h.w;

  unsigned g = h0 + h1 + h2 + h3;
  unsigned s = g;
#pragma unroll
  for (int d = 1; d < 64; d <<= 1) {
    unsigned o = __shfl_down(s, d, 64);
    if (lane + d < 64) s += o;
  }
  if (lane == 0) wtot[wid] = s;
  __syncthreads();
  if (tid < 16) {
    unsigned t = wtot[tid];
#pragma unroll
    for (int d = 1; d < 16; d <<= 1) {
      unsigned o = __shfl_down(t, d, 64);
      if (tid + d < 16) t += o;
    }
    wtot[tid] = t;
  }
  __syncthreads();
  unsigned S = s + ((wid < 15) ? wtot[wid + 1] : 0u);
  if (S >= KTOP && (S - g) < KTOP) {
    unsigned acc = S - g;
    int cut;
    acc += h3;
    if (acc >= KTOP) cut = 4 * tid + 3;
    else {
      acc += h2;
      if (acc >= KTOP) cut = 4 * tid + 2;
      else {
        acc += h1;
        if (acc >= KTOP) cut = 4 * tid + 1;
        else cut = 4 * tid;
      }
    }
    cutoff_s = cut;
  }
  __syncthreads();
  const int cutoff = cutoff_s;

#pragma unroll
  for (int it = 0; it < NITER; ++it) {
    const int e = tid + (it << 10);
    if (e < NPRED) {
      float m = sc[it];
      int b = (int)(m * (float)NBINS);
      b = min(max(b, 0), NBINS - 1);
      if (b >= cutoff) {
        int p = atomicAdd(&cnt_s, 1);
        if (p < CAP) {
          keysL[p] = (((unsigned long long)__float_as_uint(m)) << 32)
                   | (unsigned)(0x7FFFFFFF - e);
        }
      }
    }
  }
  __syncthreads();
  const int cnt = min(cnt_s, CAP);
  unsigned long long key = (tid < cnt) ? keysL[tid] : 0ull;

  for (int k = 2; k <= CAP; k <<= 1) {
    for (int j = k >> 1; j > 0; j >>= 1) {
      unsigned long long p;
      if (j >= 64) {
        __syncthreads();
        keysL[tid] = key;
        __syncthreads();
        p = keysL[tid ^ j];
      } else {
        p = shflx64(key, j);
      }
      bool lower = ((tid & j) == 0);
      bool descR = ((tid & k) == 0);
      bool takeMax = (lower == descR);
      bool pGreater = (p > key);
      key = (takeMax == pGreater) ? p : key;
    }
  }

  if (tid < KTOP) {
    int gi = 0x7FFFFFFF - (int)(unsigned)(key & 0xffffffffull);
    if ((unsigned)gi >= NPRED) gi = 0;
    float v = __uint_as_float((unsigned)(key >> 32));
    const float4 a = *reinterpret_cast<const float4*>(base + (size_t)gi * 8);
    const float4 q = *reinterpret_cast<const float4*>(base + (size_t)gi * 8 + 4);
    float p0 = q.x * q.y, p1 = q.x * q.z, p2 = q.x * q.w;
    float m = fmaxf(p0, fmaxf(p1, p2));
    int c = (p0 == m) ? 0 : ((p1 == m) ? 1 : 2);
    float x0 = a.x - a.z * 0.5f;
    float y0 = a.y - a.w * 0.5f;
    float x1 = a.x + a.z * 0.5f;
    float y1 = a.y + a.w * 0.5f;
    float co = (float)c * MAXWH;
    bx0[tid] = x0; bx1[tid] = y0; bx2[tid] = x1; bx3[tid] = y1;
    float o0 = x0 + co, o1 = y0 + co, o2 = x1 + co, o3 = y1 + co;
    ox0[tid] = o0; oy0[tid] = o1; ox1[tid] = o2; oy1[tid] = o3;
    areaL[tid] = (o2 - o0) * (o3 - o1);
    cidL[tid] = c;
    svL[tid] = v; siL[tid] = gi;
  }
  __syncthreads();
  for (int w = tid; w < KTOP * MSTRIDE; w += NTHR) maskA[w] = 0u;
  __syncthreads();

  {
    for (int jb = 0; jb < 8; ++jb) {
      const int j = (jb << 6) + lane;
      const float jx0 = ox0[j], jy0 = oy0[j], jx1 = ox1[j], jy1 = oy1[j];
      const float ja = areaL[j];
      const int ilim = (jb + 1) << 6;
      for (int i = wid; i < ilim; i += 16) {
        const float ix0 = ox0[i], iy0 = oy0[i], ix1 = ox1[i], iy1 = oy1[i];
        const float ia = areaL[i];
        float xx0 = fmaxf(ix0, jx0);
        float yy0 = fmaxf(iy0, jy0);
        float xx1 = fminf(ix1, jx1);
        float yy1 = fminf(iy1, jy1);
        float iw = fmaxf(xx1 - xx0, 0.0f);
        float ih = fmaxf(yy1 - yy0, 0.0f);
        float inter = iw * ih;
        float denom = ia + ja - inter + 1e-7f;
        bool sup = (inter > IOU_T * denom) && (j > i);
        unsigned long long bal = __ballot(sup);
        if (lane == 0) {
          *reinterpret_cast<unsigned long long*>(maskA + i * MSTRIDE + (jb << 1)) = bal;
        }
      }
    }
  }
  __syncthreads();

  if (tid < 16) {
    unsigned sst = 0u;
    for (int c = 0; c < KTOP / 16; ++c) {
      const int rb = c * 16;
      const int wi = rb >> 5;
      const int b0 = rb & 31;
      unsigned myrow[16], diag[16];
#pragma unroll
      for (int r = 0; r < 16; ++r) {
        myrow[r] = maskA[(rb + r) * MSTRIDE + tid];
        diag[r]  = maskA[(rb + r) * MSTRIDE + wi];
      }
      unsigned wcur = __shfl(sst, wi, 64);
#pragma unroll
      for (int r = 0; r < 16; ++r) {
        if (!((wcur >> (b0 + r)) & 1u)) { sst |= myrow[r]; wcur |= diag[r]; }
      }
    }
    supW[tid] = sst;
  }
  __syncthreads();

  bool keep = false;
  float score = 0.0f;
  if (tid < KTOP) {
    keep = !((supW[tid >> 5] >> (tid & 31)) & 1u);
    score = svL[tid];
  }
  unsigned long long balK = __ballot(keep);
  int wpre = __popcll(balK & ((1ull << lane) - 1ull));
  if (lane == 63 && wid < 8) wtot[wid] = (unsigned)(wpre + (keep ? 1 : 0));
  __syncthreads();
  if (tid == 0) {
    int a = 0;
    for (int w = 0; w < 8; ++w) { woff[w] = a; a += (int)wtot[w]; }
  }
  __syncthreads();
  bool valid = false;
  if (tid < KTOP) {
    int rank = woff[wid] + wpre + (keep ? 1 : 0);
    valid = keep && ((score > CONF_T) || (rank <= 1));
  }
  __syncthreads();
  unsigned long long balV = __ballot(valid);
  int vpre = __popcll(balV & ((1ull << lane) - 1ull));
  if (lane == 63 && wid < 8) wtot[wid] = (unsigned)(vpre + (valid ? 1 : 0));
  __syncthreads();
  if (tid == 0) {
    int a = 0;
    for (int w = 0; w < 8; ++w) { woff[w] = a; a += (int)wtot[w]; }
    nvalid_s = a;
  }
  __syncthreads();
  if (tid < KTOP) {
    int vs = woff[wid] + vpre + (valid ? 1 : 0);
    int nvalid = nvalid_s;
    int pos = valid ? (vs - 1) : (nvalid + tid - vs);
    if (pos < MAXDET) {
      const int SB = BS * MAXDET;
      float* outBoxes  = out;
      float* outScores = out + (size_t)SB * 4;
      float* outCls    = outScores + SB;
      float* outIds    = outCls + SB;
      float* outValid  = outIds + SB;
      size_t row = (size_t)img * MAXDET + pos;
      if (valid) {
        outBoxes[row * 4 + 0] = bx0[tid];
        outBoxes[row * 4 + 1] = bx1[tid];
        outBoxes[row * 4 + 2] = bx2[tid];
        outBoxes[row * 4 + 3] = bx3[tid];
        outScores[row] = score;
      } else {
        outBoxes[row * 4 + 0] = 0.0f;
        outBoxes[row * 4 + 1] = 0.0f;
        outBoxes[row * 4 + 2] = 0.0f;
        outBoxes[row * 4 + 3] = 0.0f;
        outScores[row] = 0.0f;
      }
      outCls[row]   = (float)cidL[tid];
      outIds[row]   = (float)(siL[tid] / 3);
      outValid[row] = valid ? 1.0f : 0.0f;
    }
  }
}

extern "C" void kernel_launch(void* const* d_in, const int* in_sizes, int n_in,
                              void* d_out, int out_size, void* d_ws, size_t ws_size,
                              hipStream_t stream) {
  (void)in_sizes; (void)n_in; (void)out_size;
  const float* pred = (const float*)d_in[0];
  float* out = (float*)d_out;
  // --- instrumentation probes (one-round phase ablation; results -> ws) ---
  if (d_ws != nullptr && ws_size >= (size_t)2 * 1024 * 1024) {
    unsigned long long* wsk = (unsigned long long*)d_ws;                 // 512 KB
    unsigned long long* wsj = wsk + (size_t)BS * CAP;                    // 512 KB
    unsigned int* wso = (unsigned int*)(wsj + (size_t)BS * CAP);         // 4 KB
    float* wsl = (float*)(wso + (size_t)BS * 16);                        // 256 KB
    probe_load_k<<<BS, NTHR, 0, stream>>>(pred, wsl);
    probe_scan_k<<<BS, NTHR, 0, stream>>>(pred, wsk);
    probe_sort_k<<<BS, NTHR, 0, stream>>>(wsj);
    probe_mask_k<<<BS, NTHR, 0, stream>>>(pred, wso);
  }
  yolo_k<<<BS, NTHR, 0, stream>>>(pred, out);
}

// Round 11
// 129.726 us; speedup vs baseline: 1.6333x; 1.6333x over previous
//
#include <hip/hip_runtime.h>
#include <cstdint>
#include <cstddef>

#define BS      64
#define NPRED   25200
#define KTOP    512
#define MAXDET  300
#define NBINS   4096
#define CAP     1024
#define NTHR    1024
#define CONF_T  0.25f
#define IOU_T   0.45f
#define MAXWH   7680.0f
#define MSTRIDE 18
#define NITER   25

__device__ __forceinline__ unsigned long long shflx64(unsigned long long v, int m) {
  unsigned lo = __shfl_xor((unsigned)(v & 0xffffffffull), m, 64);
  unsigned hi = __shfl_xor((unsigned)(v >> 32), m, 64);
  return (((unsigned long long)hi) << 32) | lo;
}

__device__ __forceinline__ float scoreOf(const float4& q) {
  return fmaxf(q.x * q.y, fmaxf(q.x * q.z, q.x * q.w));
}

// Single fused kernel, one block per image. No d_ws usage.
__global__ __launch_bounds__(NTHR) void yolo_k(const float* __restrict__ pred,
                                               float* __restrict__ out) {
  __shared__ unsigned long long keysL[CAP];
  __shared__ __align__(16) unsigned int maskA[KTOP * MSTRIDE];  // hist overlay in A
  __shared__ float ox0[KTOP], oy0[KTOP], ox1[KTOP], oy1[KTOP];
  __shared__ float bx0[KTOP], bx1[KTOP], bx2[KTOP], bx3[KTOP];
  __shared__ float svL[KTOP]; __shared__ int siL[KTOP]; __shared__ int cidL[KTOP];
  __shared__ unsigned int supW[16];
  __shared__ unsigned int wtot[16];
  __shared__ int woff[8];
  __shared__ int cutoff_s, cnt_s, nvalid_s;

  unsigned int* hist = maskA;   // words [0,4096) — dead before E rewrites maskA

  const int tid = threadIdx.x;
  const int lane = tid & 63;
  const int wid = tid >> 6;
  const int img = blockIdx.x;
  const float* __restrict__ base = pred + (size_t)img * (NPRED * 8);

  if (tid == 0) cnt_s = 0;

  // ---- phase A: score all anchors; cache in registers; LDS histogram ----
  for (int b = tid; b < NBINS; b += NTHR) hist[b] = 0u;
  __syncthreads();
  float sc[NITER];
#pragma unroll
  for (int it = 0; it < NITER; ++it) {
    const int e = tid + (it << 10);
    float m = -1.0f;
    if (e < NPRED) {
      const float4 q = *reinterpret_cast<const float4*>(base + (size_t)e * 8 + 4);
      m = scoreOf(q);
      int b = (int)(m * (float)NBINS);
      b = min(max(b, 0), NBINS - 1);
      atomicAdd(&hist[b], 1u);
    }
    sc[it] = m;
  }
  __syncthreads();
  const uint4 h = *reinterpret_cast<const uint4*>(hist + (tid << 2));
  const unsigned h0 = h.x, h1 = h.y, h2 = h.z, h3 = h.w;

  // ---- suffix scan of per-thread 4-bin sums -> cutoff bin ----
  unsigned g = h0 + h1 + h2 + h3;
  unsigned s = g;
#pragma unroll
  for (int d = 1; d < 64; d <<= 1) {
    unsigned o = __shfl_down(s, d, 64);
    if (lane + d < 64) s += o;
  }
  if (lane == 0) wtot[wid] = s;
  __syncthreads();
  if (tid < 16) {
    unsigned t = wtot[tid];
#pragma unroll
    for (int d = 1; d < 16; d <<= 1) {
      unsigned o = __shfl_down(t, d, 64);
      if (tid + d < 16) t += o;
    }
    wtot[tid] = t;
  }
  __syncthreads();
  unsigned S = s + ((wid < 15) ? wtot[wid + 1] : 0u);
  if (S >= KTOP && (S - g) < KTOP) {   // exactly one thread
    unsigned acc = S - g;
    int cut;
    acc += h3;
    if (acc >= KTOP) cut = 4 * tid + 3;
    else {
      acc += h2;
      if (acc >= KTOP) cut = 4 * tid + 2;
      else {
        acc += h1;
        if (acc >= KTOP) cut = 4 * tid + 1;
        else cut = 4 * tid;
      }
    }
    cutoff_s = cut;
  }
  __syncthreads();
  const int cutoff = cutoff_s;

  // ---- phase B: collect candidates (bin >= cutoff) from registers ----
#pragma unroll
  for (int it = 0; it < NITER; ++it) {
    const int e = tid + (it << 10);
    if (e < NPRED) {
      float m = sc[it];
      int b = (int)(m * (float)NBINS);
      b = min(max(b, 0), NBINS - 1);
      if (b >= cutoff) {
        int p = atomicAdd(&cnt_s, 1);
        if (p < CAP) {
          keysL[p] = (((unsigned long long)__float_as_uint(m)) << 32)
                   | (unsigned)(0x7FFFFFFF - e);
        }
      }
    }
  }
  __syncthreads();
  const int cnt = min(cnt_s, CAP);
  unsigned long long key = (tid < cnt) ? keysL[tid] : 0ull;

  // ---- phase C: hybrid bitonic sort (desc); element stays in register ----
  for (int k = 2; k <= CAP; k <<= 1) {
    for (int j = k >> 1; j > 0; j >>= 1) {
      unsigned long long p;
      if (j >= 64) {
        __syncthreads();
        keysL[tid] = key;
        __syncthreads();
        p = keysL[tid ^ j];
      } else {
        p = shflx64(key, j);
      }
      bool lower = ((tid & j) == 0);
      bool descR = ((tid & k) == 0);
      bool takeMax = (lower == descR);
      bool pGreater = (p > key);
      key = (takeMax == pGreater) ? p : key;
    }
  }
  // thread tid holds sorted[tid] (desc by value, asc by index)

  // ---- phase D: build boxes for top-K ----
  if (tid < KTOP) {
    int gi = 0x7FFFFFFF - (int)(unsigned)(key & 0xffffffffull);
    if ((unsigned)gi >= NPRED) gi = 0;              // safety only
    float v = __uint_as_float((unsigned)(key >> 32));
    const float4 a = *reinterpret_cast<const float4*>(base + (size_t)gi * 8);
    const float4 q = *reinterpret_cast<const float4*>(base + (size_t)gi * 8 + 4);
    float p0 = q.x * q.y, p1 = q.x * q.z, p2 = q.x * q.w;
    float m = fmaxf(p0, fmaxf(p1, p2));
    int c = (p0 == m) ? 0 : ((p1 == m) ? 1 : 2);    // first-max == jnp.argmax
    float x0 = a.x - a.z * 0.5f;
    float y0 = a.y - a.w * 0.5f;
    float x1 = a.x + a.z * 0.5f;
    float y1 = a.y + a.w * 0.5f;
    float co = (float)c * MAXWH;
    bx0[tid] = x0; bx1[tid] = y0; bx2[tid] = x1; bx3[tid] = y1;
    ox0[tid] = x0 + co; oy0[tid] = y0 + co; ox1[tid] = x1 + co; oy1[tid] = y1 + co;
    cidL[tid] = c;
    svL[tid] = v; siL[tid] = gi;
  }
  __syncthreads();

  // ---- phase E: suppression mask, j-boxes in registers (LDS-op minimized) --
  // Lane owns j = 64*jb + lane for all 8 jb (40 VGPR preload). Wave owns rows
  // i = wid + 16t (wave-uniform -> 4 broadcast LDS reads per row). All IoU
  // work is pure VALU; one 16-lane ds_write of the full 16-word row mask.
  {
    float jx0[8], jy0[8], jx1[8], jy1[8], jA[8];
#pragma unroll
    for (int jb = 0; jb < 8; ++jb) {
      const int j = (jb << 6) + lane;
      jx0[jb] = ox0[j]; jy0[jb] = oy0[j];
      jx1[jb] = ox1[j]; jy1[jb] = oy1[j];
      jA[jb] = (jx1[jb] - jx0[jb]) * (jy1[jb] - jy0[jb]);  // == reference area
    }
    for (int t = 0; t < KTOP / 16; ++t) {
      const int i = wid + (t << 4);                 // wave-uniform row
      const float ix0 = ox0[i], iy0 = oy0[i], ix1 = ox1[i], iy1 = oy1[i];
      const float ia = (ix1 - ix0) * (iy1 - iy0);
      const int jb0 = i >> 6;
      unsigned long long b[8];
#pragma unroll
      for (int jb = 0; jb < 8; ++jb) {
        b[jb] = 0ull;
        if (jb >= jb0) {                            // wave-uniform branch
          const int j = (jb << 6) + lane;
          float xx0 = fmaxf(ix0, jx0[jb]);
          float yy0 = fmaxf(iy0, jy0[jb]);
          float xx1 = fminf(ix1, jx1[jb]);
          float yy1 = fminf(iy1, jy1[jb]);
          float iw = fmaxf(xx1 - xx0, 0.0f);
          float ih = fmaxf(yy1 - yy0, 0.0f);
          float inter = iw * ih;
          float denom = ia + jA[jb] - inter + 1e-7f;
          bool sup = (inter > IOU_T * denom) && (j > i);
          b[jb] = __ballot(sup);
        }
      }
      unsigned w = 0u;                              // word 'lane' of row i
#pragma unroll
      for (int jb = 0; jb < 8; ++jb) {
        unsigned piece = (lane & 1) ? (unsigned)(b[jb] >> 32) : (unsigned)b[jb];
        w = ((lane >> 1) == jb) ? piece : w;
      }
      if (lane < 16) maskA[i * MSTRIDE + lane] = w;
    }
  }
  __syncthreads();

  // ---- phase F: greedy walk, register-chunked (16 lanes, 512-bit state) ----
  if (tid < 16) {
    unsigned sst = 0u;
    for (int c = 0; c < KTOP / 16; ++c) {
      const int rb = c * 16;
      const int wi = rb >> 5;
      const int b0 = rb & 31;
      unsigned myrow[16], diag[16];
#pragma unroll
      for (int r = 0; r < 16; ++r) {
        myrow[r] = maskA[(rb + r) * MSTRIDE + tid];
        diag[r]  = maskA[(rb + r) * MSTRIDE + wi];
      }
      unsigned wcur = __shfl(sst, wi, 64);
#pragma unroll
      for (int r = 0; r < 16; ++r) {
        if (!((wcur >> (b0 + r)) & 1u)) { sst |= myrow[r]; wcur |= diag[r]; }
      }
    }
    supW[tid] = sst;
  }
  __syncthreads();

  // ---- phase G: rank/valid via ballot scans + stable partition pack ----
  bool keep = false;
  float score = 0.0f;
  if (tid < KTOP) {
    keep = !((supW[tid >> 5] >> (tid & 31)) & 1u);
    score = svL[tid];
  }
  unsigned long long balK = __ballot(keep);
  int wpre = __popcll(balK & ((1ull << lane) - 1ull));
  if (lane == 63 && wid < 8) wtot[wid] = (unsigned)(wpre + (keep ? 1 : 0));
  __syncthreads();
  if (tid == 0) {
    int a = 0;
    for (int w = 0; w < 8; ++w) { woff[w] = a; a += (int)wtot[w]; }
  }
  __syncthreads();
  bool valid = false;
  if (tid < KTOP) {
    int rank = woff[wid] + wpre + (keep ? 1 : 0);
    valid = keep && ((score > CONF_T) || (rank <= 1));  // MIN_DET = 1
  }
  __syncthreads();
  unsigned long long balV = __ballot(valid);
  int vpre = __popcll(balV & ((1ull << lane) - 1ull));
  if (lane == 63 && wid < 8) wtot[wid] = (unsigned)(vpre + (valid ? 1 : 0));
  __syncthreads();
  if (tid == 0) {
    int a = 0;
    for (int w = 0; w < 8; ++w) { woff[w] = a; a += (int)wtot[w]; }
    nvalid_s = a;
  }
  __syncthreads();
  if (tid < KTOP) {
    int vs = woff[wid] + vpre + (valid ? 1 : 0);
    int nvalid = nvalid_s;
    int pos = valid ? (vs - 1) : (nvalid + tid - vs);
    if (pos < MAXDET) {
      const int SB = BS * MAXDET;
      float* outBoxes  = out;                    // [BS][300][4]
      float* outScores = out + (size_t)SB * 4;   // [BS][300]
      float* outCls    = outScores + SB;
      float* outIds    = outCls + SB;
      float* outValid  = outIds + SB;
      size_t row = (size_t)img * MAXDET + pos;
      if (valid) {
        outBoxes[row * 4 + 0] = bx0[tid];
        outBoxes[row * 4 + 1] = bx1[tid];
        outBoxes[row * 4 + 2] = bx2[tid];
        outBoxes[row * 4 + 3] = bx3[tid];
        outScores[row] = score;
      } else {
        outBoxes[row * 4 + 0] = 0.0f;
        outBoxes[row * 4 + 1] = 0.0f;
        outBoxes[row * 4 + 2] = 0.0f;
        outBoxes[row * 4 + 3] = 0.0f;
        outScores[row] = 0.0f;
      }
      outCls[row]   = (float)cidL[tid];          // not masked (matches reference)
      outIds[row]   = (float)(siL[tid] / 3);     // topi // ANCHORS_PER_CELL
      outValid[row] = valid ? 1.0f : 0.0f;
    }
  }
}

extern "C" void kernel_launch(void* const* d_in, const int* in_sizes, int n_in,
                              void* d_out, int out_size, void* d_ws, size_t ws_size,
                              hipStream_t stream) {
  (void)in_sizes; (void)n_in; (void)out_size; (void)d_ws; (void)ws_size;
  const float* pred = (const float*)d_in[0];
  float* out = (float*)d_out;
  yolo_k<<<BS, NTHR, 0, stream>>>(pred, out);
}